// Round 6
// baseline (47.798 us; speedup 1.0000x reference)
//
#include <hip/hip_runtime.h>

// Problem constants: B=8, N=2048, M=2048, D=128
#define B_DIM 8
#define N_DIM 2048
#define M_DIM 2048
#define D_DIM 128
#define BM 128
#define BN 128

typedef __bf16 bf16_t;
typedef bf16_t bf16x4 __attribute__((ext_vector_type(4)));
typedef bf16_t bf16x8 __attribute__((ext_vector_type(8)));
typedef float f32x4 __attribute__((ext_vector_type(4)));

// ---------------------------------------------------------------------------
// Kernel 1: fp32 -> bf16 (RNE) + row norms, writing a PRE-FRAGMENTED layout:
// 16B granule index = g*256 + gran*16 + r
//   g = (global row)/16, r = row & 15, gran = 8-elem chunk (0..15)
// An MFMA wave fragment load (gran = kk*4 + (lane>>4), r = lane&15) is then a
// fully-coalesced 1KB global_load_dwordx4.
// ---------------------------------------------------------------------------
__global__ __launch_bounds__(256) void prep_kernel(
    const float* __restrict__ L, const float* __restrict__ R,
    bf16x8* __restrict__ LbF, bf16x8* __restrict__ RbF,
    float* __restrict__ nL, float* __restrict__ nR)
{
    __shared__ float part[256];

    const int tid  = threadIdx.x;
    const int r    = tid & 15;
    const int gran = tid >> 4;
    const int grp  = blockIdx.x;              // [0, 1024)
    const int row  = grp * 16 + r;

    const float* src  = blockIdx.y ? R : L;
    bf16x8*      dstF = blockIdx.y ? RbF : LbF;
    float*       ndst = blockIdx.y ? nR : nL;

    float4 v0 = ((const float4*)src)[(size_t)row * 32 + gran * 2];
    float4 v1 = ((const float4*)src)[(size_t)row * 32 + gran * 2 + 1];
    bf16x8 p = { (bf16_t)v0.x, (bf16_t)v0.y, (bf16_t)v0.z, (bf16_t)v0.w,
                 (bf16_t)v1.x, (bf16_t)v1.y, (bf16_t)v1.z, (bf16_t)v1.w };
    dstF[(size_t)grp * 256 + tid] = p;

    float s = 0.0f;
    #pragma unroll
    for (int j = 0; j < 8; ++j) {
        float x = (float)p[j];
        s = fmaf(x, x, s);
    }
    part[tid] = s;
    __syncthreads();
    if (tid < 16) {
        float t = 0.0f;
        #pragma unroll
        for (int k = 0; k < 16; ++k) t += part[k * 16 + tid];
        ndst[grp * 16 + tid] = t;
    }
}

// ---------------------------------------------------------------------------
// Kernel 2: barrier-free, LDS-free MFMA distance sweep.
// Each block: one 128-row A panel (fragments held in REGISTERS, loaded once),
// loops over 4 bx tiles x 2 nt-halves. Each iteration: B-fragment L2 loads ->
// 32 MFMA -> 8 nontemporal float4 stores. Stores of iter i overlap compute of
// iter i+1 (no syncthreads anywhere) => continuous write-pipe occupancy.
// MFMA operands SWAPPED (mfma(B,A)): out-row = lane&15 (A-row),
// out-col = (lane>>4)*4 + reg (B-row) => float4 stores.
// ---------------------------------------------------------------------------
#define NT_TILES 4

__global__ __launch_bounds__(256, 3) void dist_mfma_kernel(
    const bf16x8* __restrict__ LbF, const bf16x8* __restrict__ RbF,
    const float* __restrict__ nL, const float* __restrict__ nR,
    float* __restrict__ out)
{
    const int tid  = threadIdx.x;
    const int bxg  = blockIdx.x;   // tile-group along M: covers NT_TILES tiles
    const int by   = blockIdx.y;   // N tile (rows)
    const int bz   = blockIdx.z;   // batch
    const int wid  = tid >> 6;
    const int lane = tid & 63;
    const int lr   = lane & 15;
    const int h    = lane >> 4;    // 0..3

    const int wM = (wid >> 1) * 64;
    const int wN = (wid & 1) * 64;

    // ---- A fragments: loaded ONCE, reused across all tiles. af[mt][kk]
    const int gA0 = bz * 128 + by * 8 + (wid >> 1) * 4;
    bf16x8 af[4][4];
    #pragma unroll
    for (int kk = 0; kk < 4; ++kk) {
        const int gidx = (kk * 4 + h) * 16 + lr;
        #pragma unroll
        for (int mt = 0; mt < 4; ++mt)
            af[mt][kk] = LbF[(size_t)(gA0 + mt) * 256 + gidx];
    }

    // ---- L norms for this thread's 4 output rows
    float l2v[4];
    #pragma unroll
    for (int mt = 0; mt < 4; ++mt)
        l2v[mt] = nL[bz * N_DIM + by * BM + wM + mt * 16 + lr];

    // ---- Tile loop over bx
    for (int t = 0; t < NT_TILES; ++t) {
        const int bx = bxg * NT_TILES + t;
        const bf16x8* Bbase = RbF + (size_t)(bz * 128 + bx * 8 + (wid & 1) * 4) * 256;
        const float*  nRb   = nR + bz * M_DIM + bx * BN;
        const size_t outBase = ((size_t)bz * N_DIM + (size_t)by * BM) * M_DIM + (size_t)bx * BN;

        #pragma unroll
        for (int nh = 0; nh < 2; ++nh) {       // nt = nh*2 + q
            f32x4 acc[4][2] = {};
            #pragma unroll
            for (int kk = 0; kk < 4; ++kk) {
                const int gidx = (kk * 4 + h) * 16 + lr;
                bf16x8 bfr[2];
                #pragma unroll
                for (int q = 0; q < 2; ++q)
                    bfr[q] = Bbase[(size_t)(nh * 2 + q) * 256 + gidx];
                #pragma unroll
                for (int mt = 0; mt < 4; ++mt)
                    #pragma unroll
                    for (int q = 0; q < 2; ++q)
                        acc[mt][q] = __builtin_amdgcn_mfma_f32_16x16x32_bf16(
                            bfr[q], af[mt][kk], acc[mt][q], 0, 0, 0);
            }

            // R norms for the 2 column chunks of this half
            f32x4 r2h[2];
            #pragma unroll
            for (int q = 0; q < 2; ++q)
                r2h[q] = *(const f32x4*)&nRb[wN + (nh * 2 + q) * 16 + h * 4];

            // epilogue + nontemporal float4 stores
            #pragma unroll
            for (int mt = 0; mt < 4; ++mt) {
                const int row_l = wM + mt * 16 + lr;
                const float l2 = l2v[mt];
                float* orow = out + outBase + (size_t)row_l * M_DIM;
                #pragma unroll
                for (int q = 0; q < 2; ++q) {
                    const int colb = wN + (nh * 2 + q) * 16 + h * 4;
                    f32x4 a = acc[mt][q];
                    f32x4 o;
                    #pragma unroll
                    for (int r = 0; r < 4; ++r) {
                        float d2 = fmaf(-2.0f, a[r], l2 + r2h[q][r]);
                        d2 = fmaxf(d2, 0.0f);
                        float s = __builtin_amdgcn_sqrtf(d2);
                        o[r] = __builtin_amdgcn_rcpf(1.0f + s);
                    }
                    __builtin_nontemporal_store(o, (f32x4*)(orow + colb));
                }
            }
        }
    }
}

// ---------------------------------------------------------------------------
// Fallback (self-contained, no ws) in case ws_size is too small.
// ---------------------------------------------------------------------------
__device__ inline unsigned short f32_to_bf16_rne(float f) {
    unsigned u = __float_as_uint(f);
    u += 0x7FFFu + ((u >> 16) & 1u);
    return (unsigned short)(u >> 16);
}

typedef bf16_t bf16x8_fb __attribute__((ext_vector_type(8)));

__global__ __launch_bounds__(256) void attn_dist_fallback(
    const float* __restrict__ L, const float* __restrict__ R,
    float* __restrict__ out)
{
    __shared__ unsigned short Als[BM * D_DIM];
    __shared__ unsigned short Bls[BN * D_DIM];
    __shared__ float normA[BM];
    __shared__ float normB[BN];

    const int tid = threadIdx.x;
    const int bx = blockIdx.x, by = blockIdx.y, bz = blockIdx.z;

    const float* aSrc = L + ((size_t)bz * N_DIM + (size_t)by * BM) * D_DIM;
    const float* bSrc = R + ((size_t)bz * M_DIM + (size_t)bx * BN) * D_DIM;

    char* AlsB = (char*)Als;
    char* BlsB = (char*)Bls;

    #pragma unroll
    for (int i = 0; i < 16; ++i) {
        int idx = tid + i * 256;
        int row = idx >> 5;
        int c4  = idx & 31;
        float4 va = ((const float4*)aSrc)[idx];
        float4 vb = ((const float4*)bSrc)[idx];
        ushort4 pa, pb;
        pa.x = f32_to_bf16_rne(va.x); pa.y = f32_to_bf16_rne(va.y);
        pa.z = f32_to_bf16_rne(va.z); pa.w = f32_to_bf16_rne(va.w);
        pb.x = f32_to_bf16_rne(vb.x); pb.y = f32_to_bf16_rne(vb.y);
        pb.z = f32_to_bf16_rne(vb.z); pb.w = f32_to_bf16_rne(vb.w);
        int off = row * 256 + c4 * 8;
        off ^= (row & 7) << 4;
        *(ushort4*)(AlsB + off) = pa;
        *(ushort4*)(BlsB + off) = pb;
    }
    __syncthreads();

    {
        int row = tid & 127;
        const char* base = (tid < 128) ? AlsB : BlsB;
        float s = 0.0f;
        #pragma unroll
        for (int c = 0; c < 16; ++c) {
            int off = row * 256 + c * 16;
            off ^= (row & 7) << 4;
            bf16x8 v = *(const bf16x8*)(base + off);
            #pragma unroll
            for (int j = 0; j < 8; ++j) {
                float x = (float)v[j];
                s = fmaf(x, x, s);
            }
        }
        if (tid < 128) normA[row] = s;
        else           normB[row] = s;
    }
    __syncthreads();

    const int wid  = tid >> 6;
    const int lane = tid & 63;
    const int wM = (wid >> 1) * 64;
    const int wN = (wid & 1) * 64;
    const int lr = lane & 15;

    f32x4 acc[4][4] = {};

    #pragma unroll
    for (int kk = 0; kk < 4; ++kk) {
        bf16x8 af[4], bfr[4];
        #pragma unroll
        for (int t = 0; t < 4; ++t) {
            int arow = wM + t * 16 + lr;
            int aoff = arow * 256 + (kk * 32 + (lane >> 4) * 8) * 2;
            aoff ^= (arow & 7) << 4;
            af[t] = *(const bf16x8*)(AlsB + aoff);
            int brow = wN + t * 16 + lr;
            int boff = brow * 256 + (kk * 32 + (lane >> 4) * 8) * 2;
            boff ^= (brow & 7) << 4;
            bfr[t] = *(const bf16x8*)(BlsB + boff);
        }
        #pragma unroll
        for (int mt = 0; mt < 4; ++mt)
            #pragma unroll
            for (int nt = 0; nt < 4; ++nt)
                acc[mt][nt] = __builtin_amdgcn_mfma_f32_16x16x32_bf16(
                    bfr[nt], af[mt], acc[mt][nt], 0, 0, 0);
    }

    const size_t outBase = ((size_t)bz * N_DIM + (size_t)by * BM) * M_DIM + (size_t)bx * BN;
    #pragma unroll
    for (int mt = 0; mt < 4; ++mt) {
        const int row_l = wM + mt * 16 + lr;
        const float l2 = normA[row_l];
        float* orow = out + outBase + (size_t)row_l * M_DIM;
        #pragma unroll
        for (int nt = 0; nt < 4; ++nt) {
            const int colb = wN + nt * 16 + (lane >> 4) * 4;
            f32x4 r2v = *(const f32x4*)&normB[colb];
            f32x4 a = acc[mt][nt];
            f32x4 o;
            #pragma unroll
            for (int r = 0; r < 4; ++r) {
                float d2 = fmaf(-2.0f, a[r], l2 + r2v[r]);
                d2 = fmaxf(d2, 0.0f);
                float s = __builtin_amdgcn_sqrtf(d2);
                o[r] = __builtin_amdgcn_rcpf(1.0f + s);
            }
            *(f32x4*)(orow + colb) = o;
        }
    }
}

extern "C" void kernel_launch(void* const* d_in, const int* in_sizes, int n_in,
                              void* d_out, int out_size, void* d_ws, size_t ws_size,
                              hipStream_t stream) {
    const float* L = (const float*)d_in[0];
    const float* R = (const float*)d_in[1];
    float* out = (float*)d_out;

    const size_t LB_BYTES = (size_t)B_DIM * N_DIM * D_DIM * 2;  // 4 MiB
    const size_t NL_BYTES = (size_t)B_DIM * N_DIM * 4;          // 64 KiB
    const size_t need = 2 * LB_BYTES + 2 * NL_BYTES;

    if (ws_size >= need) {
        char* ws = (char*)d_ws;
        bf16x8* LbF = (bf16x8*)ws;
        bf16x8* RbF = (bf16x8*)(ws + LB_BYTES);
        float*  nLp = (float*)(ws + 2 * LB_BYTES);
        float*  nRp = (float*)(ws + 2 * LB_BYTES + NL_BYTES);

        prep_kernel<<<dim3(1024, 2, 1), dim3(256), 0, stream>>>(L, R, LbF, RbF, nLp, nRp);
        dist_mfma_kernel<<<dim3(M_DIM / (BN * NT_TILES), N_DIM / BM, B_DIM), dim3(256), 0, stream>>>(
            LbF, RbF, nLp, nRp, out);
    } else {
        attn_dist_fallback<<<dim3(M_DIM / BN, N_DIM / BM, B_DIM), dim3(256), 0, stream>>>(L, R, out);
    }
}

// Round 7
// 41.929 us; speedup vs baseline: 1.1400x; 1.1400x over previous
//
#include <hip/hip_runtime.h>

// Problem constants: B=8, N=2048, M=2048, D=128
#define B_DIM 8
#define N_DIM 2048
#define M_DIM 2048
#define D_DIM 128
#define NT_TILES 4

typedef __bf16 bf16_t;
typedef bf16_t bf16x8 __attribute__((ext_vector_type(8)));
typedef float f32x4 __attribute__((ext_vector_type(4)));

// lgkm-only barrier: does NOT drain vmcnt, so global stores stay in flight
// across tile boundaries (unlike __syncthreads, which the compiler guards
// with s_waitcnt vmcnt(0)).
__device__ __forceinline__ void lgkm_barrier() {
    asm volatile("s_waitcnt lgkmcnt(0)" ::: "memory");
    __builtin_amdgcn_s_barrier();
}

// ---------------------------------------------------------------------------
// Fused kernel. Block = 128 (A rows) x 512 (B rows, as 4 tiles of 128).
// LDS: A panel 32KB (staged once) + B tile 32KB (re-staged per tile) + norms.
// Fragmented LDS layout, granule index gi = gran*16 + (r ^ gran):
//   write phase (16 lanes, gran varies) -> 2-way banks (free)
//   read  phase (16 lanes, lr varies)   -> 2-way banks (free)
// fp32->bf16 RNE conversion happens per tile; norms computed from the SAME
// rounded values (error ~ ||delta||, absmax ~5e-4).
// Next-tile B f32 is prefetched into regs BEFORE epilogue stores: vmcnt
// retires in-order, so the conversion's counted wait never drains the stores.
// MFMA operands SWAPPED (mfma(B,A)): out-row = lane&15, out-col =
// (lane>>4)*4 + reg => contiguous float4 stores.
// ---------------------------------------------------------------------------
__global__ __launch_bounds__(256, 2) void fused_dist_kernel(
    const float* __restrict__ L, const float* __restrict__ R,
    float* __restrict__ out)
{
    __shared__ bf16x8 Als[2048];   // 32 KB
    __shared__ bf16x8 Bls[2048];   // 32 KB
    __shared__ float nAs[128];
    __shared__ float nBs[128];

    const int tid  = threadIdx.x;
    const int bxg  = blockIdx.x;   // covers NT_TILES bx tiles
    const int by   = blockIdx.y;
    const int bz   = blockIdx.z;
    const int wid  = tid >> 6;
    const int lane = tid & 63;
    const int lr   = lane & 15;
    const int h    = lane >> 4;    // 0..3
    const int r    = tid >> 4;     // staging: row within 16-row group
    const int gran = tid & 15;     // staging: 8-elem chunk

    const float* Asrc = L + ((size_t)bz * N_DIM + (size_t)by * 128) * D_DIM;
    const float* Rbat = R + (size_t)bz * M_DIM * D_DIM;

    // ---- initial stage: A panel
    #pragma unroll
    for (int i = 0; i < 8; ++i) {
        int row = i * 16 + r;
        float4 v0 = ((const float4*)Asrc)[(size_t)row * 32 + gran * 2];
        float4 v1 = ((const float4*)Asrc)[(size_t)row * 32 + gran * 2 + 1];
        bf16x8 p = { (bf16_t)v0.x, (bf16_t)v0.y, (bf16_t)v0.z, (bf16_t)v0.w,
                     (bf16_t)v1.x, (bf16_t)v1.y, (bf16_t)v1.z, (bf16_t)v1.w };
        Als[i * 256 + gran * 16 + (r ^ gran)] = p;
        float s = 0.0f;
        #pragma unroll
        for (int j = 0; j < 8; ++j) { float x = (float)p[j]; s = fmaf(x, x, s); }
        s += __shfl_xor(s, 1); s += __shfl_xor(s, 2);
        s += __shfl_xor(s, 4); s += __shfl_xor(s, 8);
        if (gran == 0) nAs[i * 16 + r] = s;
    }
    // ---- initial stage: B tile 0
    {
        const float* Bsrc = Rbat + (size_t)(bxg * NT_TILES) * 128 * D_DIM;
        #pragma unroll
        for (int i = 0; i < 8; ++i) {
            int row = i * 16 + r;
            float4 v0 = ((const float4*)Bsrc)[(size_t)row * 32 + gran * 2];
            float4 v1 = ((const float4*)Bsrc)[(size_t)row * 32 + gran * 2 + 1];
            bf16x8 p = { (bf16_t)v0.x, (bf16_t)v0.y, (bf16_t)v0.z, (bf16_t)v0.w,
                         (bf16_t)v1.x, (bf16_t)v1.y, (bf16_t)v1.z, (bf16_t)v1.w };
            Bls[i * 256 + gran * 16 + (r ^ gran)] = p;
            float s = 0.0f;
            #pragma unroll
            for (int j = 0; j < 8; ++j) { float x = (float)p[j]; s = fmaf(x, x, s); }
            s += __shfl_xor(s, 1); s += __shfl_xor(s, 2);
            s += __shfl_xor(s, 4); s += __shfl_xor(s, 8);
            if (gran == 0) nBs[i * 16 + r] = s;
        }
    }
    lgkm_barrier();

    // ---- A fragments + L norms held in registers for all tiles
    const int wM = (wid >> 1) * 64;
    const int wN = (wid & 1) * 64;
    const int agrp = (wid >> 1) * 4;
    const int bgrp = (wid & 1) * 4;

    bf16x8 af[4][4];
    #pragma unroll
    for (int kk = 0; kk < 4; ++kk) {
        int gr = kk * 4 + h;
        int gi = gr * 16 + (lr ^ gr);
        #pragma unroll
        for (int mt = 0; mt < 4; ++mt)
            af[mt][kk] = Als[(agrp + mt) * 256 + gi];
    }
    float l2v[4];
    #pragma unroll
    for (int mt = 0; mt < 4; ++mt) l2v[mt] = nAs[wM + mt * 16 + lr];

    // ---- tile loop
    for (int t = 0; t < NT_TILES; ++t) {
        const int bx = bxg * NT_TILES + t;

        // 1. MFMA on current B tile
        f32x4 acc[4][4] = {};
        #pragma unroll
        for (int kk = 0; kk < 4; ++kk) {
            int gr = kk * 4 + h;
            int gi = gr * 16 + (lr ^ gr);
            bf16x8 bfr[4];
            #pragma unroll
            for (int q = 0; q < 4; ++q)
                bfr[q] = Bls[(bgrp + q) * 256 + gi];
            #pragma unroll
            for (int mt = 0; mt < 4; ++mt)
                #pragma unroll
                for (int q = 0; q < 4; ++q)
                    acc[mt][q] = __builtin_amdgcn_mfma_f32_16x16x32_bf16(
                        bfr[q], af[mt][kk], acc[mt][q], 0, 0, 0);
        }

        // 2. prefetch next B tile (f32) into regs BEFORE stores are issued,
        //    so the later conversion wait is a counted vmcnt (stores keep flowing)
        float4 pf0[8], pf1[8];
        if (t + 1 < NT_TILES) {
            const float* Bsrc = Rbat + (size_t)(bx + 1) * 128 * D_DIM;
            #pragma unroll
            for (int i = 0; i < 8; ++i) {
                int row = i * 16 + r;
                pf0[i] = ((const float4*)Bsrc)[(size_t)row * 32 + gran * 2];
                pf1[i] = ((const float4*)Bsrc)[(size_t)row * 32 + gran * 2 + 1];
            }
        }

        // 3. epilogue + stores (reads nBs before it is overwritten)
        f32x4 r2v[4];
        #pragma unroll
        for (int q = 0; q < 4; ++q)
            r2v[q] = *(const f32x4*)&nBs[wN + q * 16 + h * 4];
        const size_t outBase =
            ((size_t)bz * N_DIM + (size_t)by * 128) * M_DIM + (size_t)bx * 128;
        #pragma unroll
        for (int mt = 0; mt < 4; ++mt) {
            const int row_l = wM + mt * 16 + lr;
            const float l2 = l2v[mt];
            float* orow = out + outBase + (size_t)row_l * M_DIM;
            #pragma unroll
            for (int q = 0; q < 4; ++q) {
                f32x4 a = acc[mt][q];
                f32x4 o;
                #pragma unroll
                for (int e = 0; e < 4; ++e) {
                    float d2 = fmaf(-2.0f, a[e], l2 + r2v[q][e]);
                    d2 = fmaxf(d2, 0.0f);
                    float sq = __builtin_amdgcn_sqrtf(d2);
                    o[e] = __builtin_amdgcn_rcpf(1.0f + sq);
                }
                *(f32x4*)(orow + wN + q * 16 + h * 4) = o;
            }
        }

        // 4-6. stage next B tile from prefetched regs (lgkm-only barriers:
        //      output stores remain in flight)
        if (t + 1 < NT_TILES) {
            lgkm_barrier();                       // all waves done reading Bls/nBs
            #pragma unroll
            for (int i = 0; i < 8; ++i) {
                bf16x8 p = { (bf16_t)pf0[i].x, (bf16_t)pf0[i].y,
                             (bf16_t)pf0[i].z, (bf16_t)pf0[i].w,
                             (bf16_t)pf1[i].x, (bf16_t)pf1[i].y,
                             (bf16_t)pf1[i].z, (bf16_t)pf1[i].w };
                Bls[i * 256 + gran * 16 + (r ^ gran)] = p;
                float s = 0.0f;
                #pragma unroll
                for (int j = 0; j < 8; ++j) { float x = (float)p[j]; s = fmaf(x, x, s); }
                s += __shfl_xor(s, 1); s += __shfl_xor(s, 2);
                s += __shfl_xor(s, 4); s += __shfl_xor(s, 8);
                if (gran == 0) nBs[i * 16 + r] = s;
            }
            lgkm_barrier();                       // staging visible to all waves
        }
    }
}

extern "C" void kernel_launch(void* const* d_in, const int* in_sizes, int n_in,
                              void* d_out, int out_size, void* d_ws, size_t ws_size,
                              hipStream_t stream) {
    const float* L = (const float*)d_in[0];
    const float* R = (const float*)d_in[1];
    float* out = (float*)d_out;

    dim3 grid(M_DIM / (128 * NT_TILES), N_DIM / 128, B_DIM);  // 4 x 16 x 8 = 512
    dim3 block(256);
    fused_dist_kernel<<<grid, block, 0, stream>>>(L, R, out);
}